// Round 17
// baseline (294.606 us; speedup 1.0000x reference)
//
#include <hip/hip_runtime.h>
#include <math.h>

// Pin FP contraction OFF (r8-r16 proven): every a*b+c stays rounded mul +
// rounded add. Explicit fmaf used only where exact (+-1).
#pragma clang fp contract(off)

#define EPSF 1e-10f
#define INV128 0.0078125f
#define C128 0.08838834764831845f   // np.float32(1/sqrt(128))

struct CbArg { float cb[128]; };

// ---------------- cross-lane primitives (r5/r9 HW-verified, pure DPP) -------
template<int CTRL>
__device__ __forceinline__ float fdpp(float v) {
    return __builtin_bit_cast(float,
        __builtin_amdgcn_update_dpp(0, __builtin_bit_cast(int, v), CTRL, 0xF, 0xF, true));
}
// xor4 as pure DPP: banks 0,2 take row_ror:4; banks 1,3 take row_ror:12.
__device__ __forceinline__ float dpp_xor4(float v) {
    const int x = __builtin_bit_cast(int, v);
    int t = __builtin_amdgcn_update_dpp(x, x, 0x124, 0xF, 0x5, false);
    t = __builtin_amdgcn_update_dpp(t, x, 0x12C, 0xF, 0xA, false);
    return __builtin_bit_cast(float, t);
}
// MODE 1: DPP (verified at runtime) | MODE 0: __shfl_xor fallback
template<int MODE, int D>
__device__ __forceinline__ float xl(float v) {
    if constexpr (MODE == 0)   return __shfl_xor(v, D, 64);
    else if constexpr (D == 1) return fdpp<0xB1>(v);   // quad_perm xor1
    else if constexpr (D == 2) return fdpp<0x4E>(v);   // quad_perm xor2
    else                       return dpp_xor4(v);     // xor4
}

__device__ __forceinline__ bool dpp_ok() {
    const int lane = threadIdx.x & 63;
    const float tv = __int_as_float(0x3f800000 + lane * 1024);
    bool ok = true;
    ok = ok && (__float_as_uint(xl<1,1>(tv)) == __float_as_uint(__shfl_xor(tv, 1, 64)));
    ok = ok && (__float_as_uint(xl<1,2>(tv)) == __float_as_uint(__shfl_xor(tv, 2, 64)));
    ok = ok && (__float_as_uint(xl<1,4>(tv)) == __float_as_uint(__shfl_xor(tv, 4, 64)));
    return __all((int)ok) != 0;
}

// ---------------------------------------------------------------------------
// Main kernel, E=16 layout (r12 DAG), register-dieted for VGPR<=64:
// fused reduction trees (r16-verified bitwise), rc aliased onto u,
// interleaved gamma trees, constants reloaded at each use site.
// ---------------------------------------------------------------------------
__device__ __forceinline__ float lm_recon(const float4* __restrict__ tbl4, float v) {
    float cf = fminf(fmaxf(fmaf(v, 128.0f, 512.0f), 0.0f), 1023.0f);
    const float4 e = tbl4[(int)cf];
    return (e.x < v) ? e.z : e.y;   // searchsorted side='left'
}

__device__ __forceinline__ void fwht_in16(float* u) {
#pragma unroll
    for (int d = 1; d <= 8; d <<= 1)
#pragma unroll
        for (int j = 0; j < 16; ++j)
            if ((j & d) == 0) {
                const float a = u[j], b = u[j + d];
                u[j] = a + b; u[j + d] = a - b;
            }
}

template<int MODE>
__device__ __forceinline__ void fwht128g(float* u, float s1, float s2, float s4) {
    fwht_in16(u);
#pragma unroll
    for (int j = 0; j < 16; ++j) { const float p = xl<MODE,1>(u[j]); u[j] = fmaf(s1, u[j], p); }
#pragma unroll
    for (int j = 0; j < 16; ++j) { const float p = xl<MODE,2>(u[j]); u[j] = fmaf(s2, u[j], p); }
#pragma unroll
    for (int j = 0; j < 16; ++j) { const float p = xl<MODE,4>(u[j]); u[j] = fmaf(s4, u[j], p); }
}

// fold an 8-partial tree (same binary structure as r12's q[] tree) + xor 1,2,4
template<int MODE>
__device__ __forceinline__ float rfold8(const float* t8) {
    float t4[4];
#pragma unroll
    for (int k = 0; k < 4; ++k) t4[k] = t8[2*k] + t8[2*k+1];
    const float t2a = t4[0] + t4[1];
    const float t2b = t4[2] + t4[3];
    float s = t2a + t2b;
    s += xl<MODE, 1>(s);
    s += xl<MODE, 2>(s);
    s += xl<MODE, 4>(s);
    return s;
}
// fused sum-of-squares (r16-verified bitwise vs r12's materialized q[])
template<int MODE>
__device__ __forceinline__ float rtree_sq(const float* u) {
    float t8[8];
#pragma unroll
    for (int k = 0; k < 8; ++k) t8[k] = (u[2*k] * u[2*k]) + (u[2*k+1] * u[2*k+1]);
    return rfold8<MODE>(t8);
}

template<int MODE>
__device__ __forceinline__ void run_groups(
        const float* __restrict__ x, float* __restrict__ out,
        const float* __restrict__ rot, const float* __restrict__ qjl,
        const float4* __restrict__ tbl4, int nrows) {
    const int t    = threadIdx.x;
    const int lane = t & 63;
    const int wid  = t >> 6;
    const int sub  = lane & 7;   // 8 lanes per row
    const int grp  = lane >> 3;  // 8 rows per wave

    const float s1 = (sub & 1) ? -1.0f : 1.0f;
    const float s2 = (sub & 2) ? -1.0f : 1.0f;
    const float s4 = (sub & 4) ? -1.0f : 1.0f;

    const int ngroups = nrows >> 3;
    const int gstride = gridDim.x * 4;

    for (int g0 = blockIdx.x * 4 + wid; g0 < ngroups; g0 += gstride) {
        const int row = g0 * 8 + grp;
        const float* xp = x + (size_t)row * 128 + sub * 16;

        float u[16], c0[16];
#pragma unroll
        for (int k = 0; k < 4; ++k) {
            const float4 v4 = ((const float4*)xp)[k];
            u[4*k] = v4.x; u[4*k+1] = v4.y; u[4*k+2] = v4.z; u[4*k+3] = v4.w;
        }

        // ---- norm, unit vector (fused tree) ----
        const float nu = sqrtf(rtree_sq<MODE>(u));
        const float iu = 1.0f / (nu + EPSF);

#pragma unroll
        for (int k = 0; k < 4; ++k) {   // rs0
            const float4 v4 = ((const float4*)(rot + sub * 16))[k];
            c0[4*k] = v4.x; c0[4*k+1] = v4.y; c0[4*k+2] = v4.z; c0[4*k+3] = v4.w;
        }
#pragma unroll
        for (int j = 0; j < 16; ++j) { u[j] = u[j] * iu; u[j] = u[j] * c0[j]; }

        // ---- rotation_fwd (normalized; feeds quantizer) ----
        fwht128g<MODE>(u, s1, s2, s4);
#pragma unroll
        for (int j = 0; j < 16; ++j) u[j] *= C128;
#pragma unroll
        for (int k = 0; k < 4; ++k) {   // rs1
            const float4 v4 = ((const float4*)(rot + 128 + sub * 16))[k];
            c0[4*k] = v4.x; c0[4*k+1] = v4.y; c0[4*k+2] = v4.z; c0[4*k+3] = v4.w;
        }
#pragma unroll
        for (int j = 0; j < 16; ++j) u[j] *= c0[j];
        fwht128g<MODE>(u, s1, s2, s4);
#pragma unroll
        for (int j = 0; j < 16; ++j) u[j] *= C128;

        // ---- pass 1: numerical rms + LM quantize + gamma (interleaved
        //      num/den partial trees; each tree's chain order == r12) ----
        const float rms = sqrtf(rtree_sq<MODE>(u)) * C128;
        const float si  = 1.0f / (rms + EPSF);
        float t8n[8], t8d[8];
#pragma unroll
        for (int k = 0; k < 8; ++k) {
            const float r0 = lm_recon(tbl4, u[2*k] * si);
            const float r1 = lm_recon(tbl4, u[2*k+1] * si);
            t8n[k] = (u[2*k] * r0) + (u[2*k+1] * r1);
            t8d[k] = (r0 * r0) + (r1 * r1);
        }
        const float num = rfold8<MODE>(t8n);
        const float den = rfold8<MODE>(t8d);
        const float gamma = num / (den + EPSF);
        const float gi    = 1.0f / (gamma + EPSF);

        // ---- MSE-stage quantize; rc aliased onto u; resn partials fused ----
        float p[16], t8[8];
#pragma unroll
        for (int k = 0; k < 8; ++k) {
            const float tq0 = lm_recon(tbl4, u[2*k] * gi);
            const float tq1 = lm_recon(tbl4, u[2*k+1] * gi);
            const float rc0 = tq0 * gamma;
            const float rc1 = tq1 * gamma;
            const float p0  = u[2*k] - rc0;
            const float p1  = u[2*k+1] - rc1;
            p[2*k] = p0; p[2*k+1] = p1;
            u[2*k] = rc0; u[2*k+1] = rc1;          // u now holds rc
            t8[k] = (p0 * p0) + (p1 * p1);
        }
        const float resn = sqrtf(rfold8<MODE>(t8));

        // ==== post-quantization (ulp-safe folds) ====
#pragma unroll
        for (int k = 0; k < 4; ++k) {   // qjl
            const float4 v4 = ((const float4*)(qjl + sub * 16))[k];
            c0[4*k] = v4.x; c0[4*k+1] = v4.y; c0[4*k+2] = v4.z; c0[4*k+3] = v4.w;
        }
#pragma unroll
        for (int j = 0; j < 16; ++j) p[j] = p[j] * c0[j];
        fwht128g<MODE>(p, s1, s2, s4);
#pragma unroll
        for (int j = 0; j < 16; ++j) p[j] = (p[j] >= 0.0f) ? 1.0f : -1.0f;
        fwht128g<MODE>(p, s1, s2, s4);   // exact integers
        const float rsc = resn * INV128;
#pragma unroll
        for (int k = 0; k < 4; ++k) {   // qjl reload (cuts liveness across FWHTs)
            const float4 v4 = ((const float4*)(qjl + sub * 16))[k];
            c0[4*k] = v4.x; c0[4*k+1] = v4.y; c0[4*k+2] = v4.z; c0[4*k+3] = v4.w;
        }
#pragma unroll
        for (int j = 0; j < 16; ++j) {
            const float tq = p[j] * c0[j];
            p[j] = fmaf(tq, rsc, u[j]);            // u holds rc; u dead after
        }

        // ---- inverse rotation (folded scales) ----
        fwht128g<MODE>(p, s1, s2, s4);
#pragma unroll
        for (int k = 0; k < 4; ++k) {   // rs1
            const float4 v4 = ((const float4*)(rot + 128 + sub * 16))[k];
            c0[4*k] = v4.x; c0[4*k+1] = v4.y; c0[4*k+2] = v4.z; c0[4*k+3] = v4.w;
        }
#pragma unroll
        for (int j = 0; j < 16; ++j) p[j] *= c0[j];
        fwht128g<MODE>(p, s1, s2, s4);
#pragma unroll
        for (int k = 0; k < 4; ++k) {   // rs0
            const float4 v4 = ((const float4*)(rot + sub * 16))[k];
            c0[4*k] = v4.x; c0[4*k+1] = v4.y; c0[4*k+2] = v4.z; c0[4*k+3] = v4.w;
        }
        const float fn = nu * INV128;
#pragma unroll
        for (int j = 0; j < 16; ++j) p[j] = (p[j] * c0[j]) * fn;

        float* op = out + (size_t)row * 128 + sub * 16;
#pragma unroll
        for (int k = 0; k < 4; ++k) {
            float4 v4;
            v4.x = p[4*k]; v4.y = p[4*k+1]; v4.z = p[4*k+2]; v4.w = p[4*k+3];
            ((float4*)op)[k] = v4;
        }
    }
}

__global__ __launch_bounds__(256, 8) void turboquant_kernel(
        const float* __restrict__ x,
        const float* __restrict__ rot,
        const float* __restrict__ qjl,
        float* __restrict__ out,
        const int nrows,
        const CbArg args) {
    __shared__ float scb[128];
    __shared__ float sbnd[128];
    __shared__ float4 tbl4[1024];

    const int t = threadIdx.x;
    if (t < 128) scb[t] = args.cb[t];
    __syncthreads();
    if (t < 128) {
        const float INF = __int_as_float(0x7f800000);
        sbnd[t] = (t < 127) ? 0.5f * (scb[t] + scb[t + 1]) : INF;
    }
    __syncthreads();
    // direct cell table (r9/r11/r12-proven): at most one boundary per
    // 1/128-wide cell (min gap ~0.034); g = #bounds < cell_left.
    for (int c = t; c < 1024; c += 256) {
        const float cl = -4.0f + (float)c * 0.0078125f;
        int g = 0;
#pragma unroll
        for (int d = 64; d >= 1; d >>= 1) g += (sbnd[g + d - 1] < cl) ? d : 0;
        tbl4[c] = make_float4(sbnd[g], scb[g], scb[(g < 127) ? g + 1 : 127], 0.0f);
    }
    __syncthreads();

    if (dpp_ok())
        run_groups<1>(x, out, rot, qjl, tbl4, nrows);
    else
        run_groups<0>(x, out, rot, qjl, tbl4, nrows);
}

// ---------------------------------------------------------------------------
// Host-side Lloyd-Max (r12-proven): token-identical f64 formulas; runs during
// capture only; kernarg struct snapshotted into the graph node.
// ---------------------------------------------------------------------------
static void lloyd_host(CbArg* out_args) {
    double lv[128], bp[127], bc[127];
    for (int i = 0; i < 128; ++i)
        lv[i] = (i == 127) ? 4.0 : (-4.0 + (8.0 / 127.0) * (double)i);

    const double inv_sqrt2pi = 0.39894228040143267794;
    const double inv_sqrt2   = 0.70710678118654752440;
    const double pdf_end = exp(-0.5 * 30.0 * 30.0) * inv_sqrt2pi;
    const double cdf_m30 = 0.5 * (1.0 + erf(-30.0 * inv_sqrt2));
    const double cdf_p30 = 0.5 * (1.0 + erf( 30.0 * inv_sqrt2));

    for (int it = 0; it < 200; ++it) {
        for (int i = 0; i < 127; ++i) {
            double tt = 0.5 * (lv[i] + lv[i + 1]);
            tt = fmin(fmax(tt, -30.0), 30.0);
            bp[i] = exp(-0.5 * tt * tt) * inv_sqrt2pi;
            bc[i] = 0.5 * (1.0 + erf(tt * inv_sqrt2));
        }
        for (int i = 0; i < 128; ++i) {
            const double plo = (i == 0)   ? pdf_end : bp[i - 1];
            const double clo = (i == 0)   ? cdf_m30 : bc[i - 1];
            const double phi = (i == 127) ? pdf_end : bp[i];
            const double chi = (i == 127) ? cdf_p30 : bc[i];
            lv[i] = (plo - phi) / fmax(chi - clo, 1e-30);
        }
    }
    for (int i = 0; i < 128; ++i) out_args->cb[i] = (float)lv[i];
}

extern "C" void kernel_launch(void* const* d_in, const int* in_sizes, int n_in,
                              void* d_out, int out_size, void* d_ws, size_t ws_size,
                              hipStream_t stream) {
    const float* x   = (const float*)d_in[0];
    const float* rot = (const float*)d_in[1];
    const float* qjl = (const float*)d_in[2];
    float* out = (float*)d_out;
    (void)d_ws; (void)ws_size;

    const int nrows = in_sizes[0] >> 7;

    CbArg args;
    lloyd_host(&args);   // pure host math; deterministic per call

    turboquant_kernel<<<2048, 256, 0, stream>>>(x, rot, qjl, out, nrows, args);
}

// Round 18
// 148.923 us; speedup vs baseline: 1.9782x; 1.9782x over previous
//
#include <hip/hip_runtime.h>
#include <math.h>

// Pin FP contraction OFF (r8-r17 proven): every a*b+c stays rounded mul +
// rounded add. Explicit fmaf used only where exact (+-1).
#pragma clang fp contract(off)

#define EPSF 1e-10f
#define INV128 0.0078125f
#define C128 0.08838834764831845f   // np.float32(1/sqrt(128))

struct CbArg { float cb[128]; };

// ---------------- cross-lane primitives (r5/r9 HW-verified, pure DPP) -------
template<int CTRL>
__device__ __forceinline__ float fdpp(float v) {
    return __builtin_bit_cast(float,
        __builtin_amdgcn_update_dpp(0, __builtin_bit_cast(int, v), CTRL, 0xF, 0xF, true));
}
// xor4 as pure DPP: banks 0,2 take row_ror:4; banks 1,3 take row_ror:12.
__device__ __forceinline__ float dpp_xor4(float v) {
    const int x = __builtin_bit_cast(int, v);
    int t = __builtin_amdgcn_update_dpp(x, x, 0x124, 0xF, 0x5, false);
    t = __builtin_amdgcn_update_dpp(t, x, 0x12C, 0xF, 0xA, false);
    return __builtin_bit_cast(float, t);
}
// MODE 1: DPP (verified at runtime) | MODE 0: __shfl_xor fallback
template<int MODE, int D>
__device__ __forceinline__ float xl(float v) {
    if constexpr (MODE == 0)   return __shfl_xor(v, D, 64);
    else if constexpr (D == 1) return fdpp<0xB1>(v);   // quad_perm xor1
    else if constexpr (D == 2) return fdpp<0x4E>(v);   // quad_perm xor2
    else                       return dpp_xor4(v);     // xor4
}

__device__ __forceinline__ bool dpp_ok() {
    const int lane = threadIdx.x & 63;
    const float tv = __int_as_float(0x3f800000 + lane * 1024);
    bool ok = true;
    ok = ok && (__float_as_uint(xl<1,1>(tv)) == __float_as_uint(__shfl_xor(tv, 1, 64)));
    ok = ok && (__float_as_uint(xl<1,2>(tv)) == __float_as_uint(__shfl_xor(tv, 2, 64)));
    ok = ok && (__float_as_uint(xl<1,4>(tv)) == __float_as_uint(__shfl_xor(tv, 4, 64)));
    return __all((int)ok) != 0;
}

// ---------------------------------------------------------------------------
// Main kernel, E=16 layout (r12 DAG), register-dieted (r17 body) with NO
// launch bound — let the allocator pick its natural (no-spill) budget.
// ---------------------------------------------------------------------------
__device__ __forceinline__ float lm_recon(const float4* __restrict__ tbl4, float v) {
    float cf = fminf(fmaxf(fmaf(v, 128.0f, 512.0f), 0.0f), 1023.0f);
    const float4 e = tbl4[(int)cf];
    return (e.x < v) ? e.z : e.y;   // searchsorted side='left'
}

__device__ __forceinline__ void fwht_in16(float* u) {
#pragma unroll
    for (int d = 1; d <= 8; d <<= 1)
#pragma unroll
        for (int j = 0; j < 16; ++j)
            if ((j & d) == 0) {
                const float a = u[j], b = u[j + d];
                u[j] = a + b; u[j + d] = a - b;
            }
}

template<int MODE>
__device__ __forceinline__ void fwht128g(float* u, float s1, float s2, float s4) {
    fwht_in16(u);
#pragma unroll
    for (int j = 0; j < 16; ++j) { const float p = xl<MODE,1>(u[j]); u[j] = fmaf(s1, u[j], p); }
#pragma unroll
    for (int j = 0; j < 16; ++j) { const float p = xl<MODE,2>(u[j]); u[j] = fmaf(s2, u[j], p); }
#pragma unroll
    for (int j = 0; j < 16; ++j) { const float p = xl<MODE,4>(u[j]); u[j] = fmaf(s4, u[j], p); }
}

// fold an 8-partial tree (same binary structure as r12's q[] tree) + xor 1,2,4
template<int MODE>
__device__ __forceinline__ float rfold8(const float* t8) {
    float t4[4];
#pragma unroll
    for (int k = 0; k < 4; ++k) t4[k] = t8[2*k] + t8[2*k+1];
    const float t2a = t4[0] + t4[1];
    const float t2b = t4[2] + t4[3];
    float s = t2a + t2b;
    s += xl<MODE, 1>(s);
    s += xl<MODE, 2>(s);
    s += xl<MODE, 4>(s);
    return s;
}
// fused sum-of-squares (r16-verified bitwise vs r12's materialized q[])
template<int MODE>
__device__ __forceinline__ float rtree_sq(const float* u) {
    float t8[8];
#pragma unroll
    for (int k = 0; k < 8; ++k) t8[k] = (u[2*k] * u[2*k]) + (u[2*k+1] * u[2*k+1]);
    return rfold8<MODE>(t8);
}

template<int MODE>
__device__ __forceinline__ void run_groups(
        const float* __restrict__ x, float* __restrict__ out,
        const float* __restrict__ rot, const float* __restrict__ qjl,
        const float4* __restrict__ tbl4, int nrows) {
    const int t    = threadIdx.x;
    const int lane = t & 63;
    const int wid  = t >> 6;
    const int sub  = lane & 7;   // 8 lanes per row
    const int grp  = lane >> 3;  // 8 rows per wave

    const float s1 = (sub & 1) ? -1.0f : 1.0f;
    const float s2 = (sub & 2) ? -1.0f : 1.0f;
    const float s4 = (sub & 4) ? -1.0f : 1.0f;

    const int ngroups = nrows >> 3;
    const int gstride = gridDim.x * 4;

    for (int g0 = blockIdx.x * 4 + wid; g0 < ngroups; g0 += gstride) {
        const int row = g0 * 8 + grp;
        const float* xp = x + (size_t)row * 128 + sub * 16;

        float u[16], c0[16];
#pragma unroll
        for (int k = 0; k < 4; ++k) {
            const float4 v4 = ((const float4*)xp)[k];
            u[4*k] = v4.x; u[4*k+1] = v4.y; u[4*k+2] = v4.z; u[4*k+3] = v4.w;
        }

        // ---- norm, unit vector (fused tree) ----
        const float nu = sqrtf(rtree_sq<MODE>(u));
        const float iu = 1.0f / (nu + EPSF);

#pragma unroll
        for (int k = 0; k < 4; ++k) {   // rs0
            const float4 v4 = ((const float4*)(rot + sub * 16))[k];
            c0[4*k] = v4.x; c0[4*k+1] = v4.y; c0[4*k+2] = v4.z; c0[4*k+3] = v4.w;
        }
#pragma unroll
        for (int j = 0; j < 16; ++j) { u[j] = u[j] * iu; u[j] = u[j] * c0[j]; }

        // ---- rotation_fwd (normalized; feeds quantizer) ----
        fwht128g<MODE>(u, s1, s2, s4);
#pragma unroll
        for (int j = 0; j < 16; ++j) u[j] *= C128;
#pragma unroll
        for (int k = 0; k < 4; ++k) {   // rs1
            const float4 v4 = ((const float4*)(rot + 128 + sub * 16))[k];
            c0[4*k] = v4.x; c0[4*k+1] = v4.y; c0[4*k+2] = v4.z; c0[4*k+3] = v4.w;
        }
#pragma unroll
        for (int j = 0; j < 16; ++j) u[j] *= c0[j];
        fwht128g<MODE>(u, s1, s2, s4);
#pragma unroll
        for (int j = 0; j < 16; ++j) u[j] *= C128;

        // ---- pass 1: numerical rms + LM quantize + gamma (interleaved
        //      num/den partial trees; each tree's chain order == r12) ----
        const float rms = sqrtf(rtree_sq<MODE>(u)) * C128;
        const float si  = 1.0f / (rms + EPSF);
        float t8n[8], t8d[8];
#pragma unroll
        for (int k = 0; k < 8; ++k) {
            const float r0 = lm_recon(tbl4, u[2*k] * si);
            const float r1 = lm_recon(tbl4, u[2*k+1] * si);
            t8n[k] = (u[2*k] * r0) + (u[2*k+1] * r1);
            t8d[k] = (r0 * r0) + (r1 * r1);
        }
        const float num = rfold8<MODE>(t8n);
        const float den = rfold8<MODE>(t8d);
        const float gamma = num / (den + EPSF);
        const float gi    = 1.0f / (gamma + EPSF);

        // ---- MSE-stage quantize; rc aliased onto u; resn partials fused ----
        float p[16], t8[8];
#pragma unroll
        for (int k = 0; k < 8; ++k) {
            const float tq0 = lm_recon(tbl4, u[2*k] * gi);
            const float tq1 = lm_recon(tbl4, u[2*k+1] * gi);
            const float rc0 = tq0 * gamma;
            const float rc1 = tq1 * gamma;
            const float p0  = u[2*k] - rc0;
            const float p1  = u[2*k+1] - rc1;
            p[2*k] = p0; p[2*k+1] = p1;
            u[2*k] = rc0; u[2*k+1] = rc1;          // u now holds rc
            t8[k] = (p0 * p0) + (p1 * p1);
        }
        const float resn = sqrtf(rfold8<MODE>(t8));

        // ==== post-quantization (ulp-safe folds) ====
#pragma unroll
        for (int k = 0; k < 4; ++k) {   // qjl
            const float4 v4 = ((const float4*)(qjl + sub * 16))[k];
            c0[4*k] = v4.x; c0[4*k+1] = v4.y; c0[4*k+2] = v4.z; c0[4*k+3] = v4.w;
        }
#pragma unroll
        for (int j = 0; j < 16; ++j) p[j] = p[j] * c0[j];
        fwht128g<MODE>(p, s1, s2, s4);
#pragma unroll
        for (int j = 0; j < 16; ++j) p[j] = (p[j] >= 0.0f) ? 1.0f : -1.0f;
        fwht128g<MODE>(p, s1, s2, s4);   // exact integers
        const float rsc = resn * INV128;
#pragma unroll
        for (int k = 0; k < 4; ++k) {   // qjl reload (cuts liveness across FWHTs)
            const float4 v4 = ((const float4*)(qjl + sub * 16))[k];
            c0[4*k] = v4.x; c0[4*k+1] = v4.y; c0[4*k+2] = v4.z; c0[4*k+3] = v4.w;
        }
#pragma unroll
        for (int j = 0; j < 16; ++j) {
            const float tq = p[j] * c0[j];
            p[j] = fmaf(tq, rsc, u[j]);            // u holds rc; u dead after
        }

        // ---- inverse rotation (folded scales) ----
        fwht128g<MODE>(p, s1, s2, s4);
#pragma unroll
        for (int k = 0; k < 4; ++k) {   // rs1
            const float4 v4 = ((const float4*)(rot + 128 + sub * 16))[k];
            c0[4*k] = v4.x; c0[4*k+1] = v4.y; c0[4*k+2] = v4.z; c0[4*k+3] = v4.w;
        }
#pragma unroll
        for (int j = 0; j < 16; ++j) p[j] *= c0[j];
        fwht128g<MODE>(p, s1, s2, s4);
#pragma unroll
        for (int k = 0; k < 4; ++k) {   // rs0
            const float4 v4 = ((const float4*)(rot + sub * 16))[k];
            c0[4*k] = v4.x; c0[4*k+1] = v4.y; c0[4*k+2] = v4.z; c0[4*k+3] = v4.w;
        }
        const float fn = nu * INV128;
#pragma unroll
        for (int j = 0; j < 16; ++j) p[j] = (p[j] * c0[j]) * fn;

        float* op = out + (size_t)row * 128 + sub * 16;
#pragma unroll
        for (int k = 0; k < 4; ++k) {
            float4 v4;
            v4.x = p[4*k]; v4.y = p[4*k+1]; v4.z = p[4*k+2]; v4.w = p[4*k+3];
            ((float4*)op)[k] = v4;
        }
    }
}

__global__ __launch_bounds__(256) void turboquant_kernel(
        const float* __restrict__ x,
        const float* __restrict__ rot,
        const float* __restrict__ qjl,
        float* __restrict__ out,
        const int nrows,
        const CbArg args) {
    __shared__ float scb[128];
    __shared__ float sbnd[128];
    __shared__ float4 tbl4[1024];

    const int t = threadIdx.x;
    if (t < 128) scb[t] = args.cb[t];
    __syncthreads();
    if (t < 128) {
        const float INF = __int_as_float(0x7f800000);
        sbnd[t] = (t < 127) ? 0.5f * (scb[t] + scb[t + 1]) : INF;
    }
    __syncthreads();
    // direct cell table (r9/r11/r12-proven): at most one boundary per
    // 1/128-wide cell (min gap ~0.034); g = #bounds < cell_left.
    for (int c = t; c < 1024; c += 256) {
        const float cl = -4.0f + (float)c * 0.0078125f;
        int g = 0;
#pragma unroll
        for (int d = 64; d >= 1; d >>= 1) g += (sbnd[g + d - 1] < cl) ? d : 0;
        tbl4[c] = make_float4(sbnd[g], scb[g], scb[(g < 127) ? g + 1 : 127], 0.0f);
    }
    __syncthreads();

    if (dpp_ok())
        run_groups<1>(x, out, rot, qjl, tbl4, nrows);
    else
        run_groups<0>(x, out, rot, qjl, tbl4, nrows);
}

// ---------------------------------------------------------------------------
// Host-side Lloyd-Max (r12-proven): token-identical f64 formulas; runs during
// capture only; kernarg struct snapshotted into the graph node.
// ---------------------------------------------------------------------------
static void lloyd_host(CbArg* out_args) {
    double lv[128], bp[127], bc[127];
    for (int i = 0; i < 128; ++i)
        lv[i] = (i == 127) ? 4.0 : (-4.0 + (8.0 / 127.0) * (double)i);

    const double inv_sqrt2pi = 0.39894228040143267794;
    const double inv_sqrt2   = 0.70710678118654752440;
    const double pdf_end = exp(-0.5 * 30.0 * 30.0) * inv_sqrt2pi;
    const double cdf_m30 = 0.5 * (1.0 + erf(-30.0 * inv_sqrt2));
    const double cdf_p30 = 0.5 * (1.0 + erf( 30.0 * inv_sqrt2));

    for (int it = 0; it < 200; ++it) {
        for (int i = 0; i < 127; ++i) {
            double tt = 0.5 * (lv[i] + lv[i + 1]);
            tt = fmin(fmax(tt, -30.0), 30.0);
            bp[i] = exp(-0.5 * tt * tt) * inv_sqrt2pi;
            bc[i] = 0.5 * (1.0 + erf(tt * inv_sqrt2));
        }
        for (int i = 0; i < 128; ++i) {
            const double plo = (i == 0)   ? pdf_end : bp[i - 1];
            const double clo = (i == 0)   ? cdf_m30 : bc[i - 1];
            const double phi = (i == 127) ? pdf_end : bp[i];
            const double chi = (i == 127) ? cdf_p30 : bc[i];
            lv[i] = (plo - phi) / fmax(chi - clo, 1e-30);
        }
    }
    for (int i = 0; i < 128; ++i) out_args->cb[i] = (float)lv[i];
}

extern "C" void kernel_launch(void* const* d_in, const int* in_sizes, int n_in,
                              void* d_out, int out_size, void* d_ws, size_t ws_size,
                              hipStream_t stream) {
    const float* x   = (const float*)d_in[0];
    const float* rot = (const float*)d_in[1];
    const float* qjl = (const float*)d_in[2];
    float* out = (float*)d_out;
    (void)d_ws; (void)ws_size;

    const int nrows = in_sizes[0] >> 7;

    CbArg args;
    lloyd_host(&args);   // pure host math; deterministic per call

    turboquant_kernel<<<2048, 256, 0, stream>>>(x, rot, qjl, out, nrows, args);
}